// Round 8
// baseline (27.979 us; speedup 1.0000x reference)
//
#include <hip/hip_runtime.h>
#include <stdint.h>

// Forward kinematics, 24-joint chain, 4 lanes/sample + Kogge-Stone scan.
// Round-8: persistent 1-wave blocks with DOUBLE-BUFFERED global_load_lds
// pipeline (counted vmcnt(9), never 0 mid-loop): tile i+1's loads stay in
// flight across tile i's compute -> continuous HBM read stream instead of
// per-block burst+drain (r6/r7 stuck at 4.3 TB/s).
// grid=2048 (8 blocks/CU, 2 waves/SIMD), 4 tiles/block of 16 samples.
// Roofline: 75.5MB in + 37.7MB out ~= 18us @ 6.3TB/s.

#define N_JOINTS 24
#define TS   16          // samples per tile (4 lanes/sample * 16 = 64 = wave)
#define GRID 2048

#define GLOAD_LDS16(gptr, lptr)                                            \
  __builtin_amdgcn_global_load_lds(                                        \
      (const __attribute__((address_space(1))) uint32_t*)(gptr),           \
      (__attribute__((address_space(3))) uint32_t*)(lptr), 16, 0, 0)

__global__ __launch_bounds__(64, 2) void fk_kernel(
    const float4* __restrict__ ain,   // angles as float4: [N*36]
    const float*  __restrict__ xyz,   // [24][3]
    float4* __restrict__ aout,        // out as float4: [N*18]
    int ntiles)
{
    __shared__ float4 s_buf[2][TS * 36];   // 2 x 9216 B tile buffers
    __shared__ float  s_t[N_JOINTS * 3];

    const int lane = threadIdx.x;          // 0..63, one wave per block
    const int s    = lane >> 2;            // local sample 0..15
    const int seg  = lane & 3;             // joints [seg*6, seg*6+6)

    // ---- local translations (joint 0 uses xyz0[0] raw) ----
    if (lane < N_JOINTS) {
        float x = xyz[lane * 3 + 0];
        float y = xyz[lane * 3 + 1];
        float z = xyz[lane * 3 + 2];
        if (lane > 0) {
            x -= xyz[lane * 3 - 3];
            y -= xyz[lane * 3 - 2];
            z -= xyz[lane * 3 - 1];
        }
        s_t[lane * 3 + 0] = x;
        s_t[lane * 3 + 1] = y;
        s_t[lane * 3 + 2] = z;
    }

    int g = blockIdx.x;
    if (g >= ntiles) return;

    // ---- prologue: issue tile g into buf 0 ----
    {
        const size_t gb = (size_t)g * (TS * 36) + lane;
        #pragma unroll
        for (int it = 0; it < 9; ++it)
            GLOAD_LDS16(ain + gb + it * 64, &s_buf[0][it * 64]);
    }

    int i = 0;
    for (; g < ntiles; g += GRID, ++i) {
        const int cur = i & 1;
        const int gn  = g + GRID;

        if (gn < ntiles) {
            // issue NEXT tile's 9 loads into the other buffer, then wait for
            // only the current tile (vmcnt(9): 9 newest stay in flight).
            const size_t gb = (size_t)gn * (TS * 36) + lane;
            #pragma unroll
            for (int it = 0; it < 9; ++it)
                GLOAD_LDS16(ain + gb + it * 64, &s_buf[cur ^ 1][it * 64]);
            asm volatile("s_waitcnt vmcnt(9)" ::: "memory");
        } else {
            asm volatile("s_waitcnt vmcnt(0)" ::: "memory");
        }
        __builtin_amdgcn_sched_barrier(0);

        // ---- compute tile from s_buf[cur] ----
        const float4* __restrict__ row = &s_buf[cur][s * 36 + seg * 9];

        float R[9], t[3];    // segment-local cumulative transform
        float o[18];         // 6 segment-local translations

        #pragma unroll
        for (int p = 0; p < 3; ++p) {           // 2 joints per float4-triple
            const float4 v0 = row[p * 3 + 0];
            const float4 v1 = row[p * 3 + 1];
            const float4 v2 = row[p * 3 + 2];
            float d6[12];
            d6[0] = v0.x; d6[1] = v0.y; d6[2]  = v0.z; d6[3]  = v0.w;
            d6[4] = v1.x; d6[5] = v1.y; d6[6]  = v1.z; d6[7]  = v1.w;
            d6[8] = v2.x; d6[9] = v2.y; d6[10] = v2.z; d6[11] = v2.w;

            #pragma unroll
            for (int h = 0; h < 2; ++h) {
                const int jl = p * 2 + h;       // 0..5 within segment
                const int j  = seg * 6 + jl;    // global joint id
                const float a1x = d6[h * 6 + 0], a1y = d6[h * 6 + 1], a1z = d6[h * 6 + 2];
                const float a2x = d6[h * 6 + 3], a2y = d6[h * 6 + 4], a2z = d6[h * 6 + 5];

                // Gram-Schmidt (Zhou 6D -> rows b1,b2,b3); rsqrtf -> v_rsq_f32
                const float inv1 = rsqrtf(a1x * a1x + a1y * a1y + a1z * a1z);
                const float b1x = a1x * inv1, b1y = a1y * inv1, b1z = a1z * inv1;
                const float dd = b1x * a2x + b1y * a2y + b1z * a2z;
                float b2x = a2x - dd * b1x, b2y = a2y - dd * b1y, b2z = a2z - dd * b1z;
                const float inv2 = rsqrtf(b2x * b2x + b2y * b2y + b2z * b2z);
                b2x *= inv2; b2y *= inv2; b2z *= inv2;
                const float b3x = b1y * b2z - b1z * b2y;
                const float b3y = b1z * b2x - b1x * b2z;
                const float b3z = b1x * b2y - b1y * b2x;
                const float Rj[9] = { b1x, b1y, b1z,  b2x, b2y, b2z,  b3x, b3y, b3z };

                const float tx = s_t[j * 3 + 0], ty = s_t[j * 3 + 1], tz = s_t[j * 3 + 2];
                const float tlx = Rj[0] * tx + Rj[1] * ty + Rj[2] * tz;
                const float tly = Rj[3] * tx + Rj[4] * ty + Rj[5] * tz;
                const float tlz = Rj[6] * tx + Rj[7] * ty + Rj[8] * tz;

                if (jl == 0) {
                    #pragma unroll
                    for (int k = 0; k < 9; ++k) R[k] = Rj[k];
                    t[0] = tlx; t[1] = tly; t[2] = tlz;
                } else {
                    t[0] += R[0] * tlx + R[1] * tly + R[2] * tlz;
                    t[1] += R[3] * tlx + R[4] * tly + R[5] * tlz;
                    t[2] += R[6] * tlx + R[7] * tly + R[8] * tlz;
                    float Nn[9];
                    #pragma unroll
                    for (int r2 = 0; r2 < 3; ++r2)
                        #pragma unroll
                        for (int c = 0; c < 3; ++c)
                            Nn[r2 * 3 + c] = R[r2 * 3 + 0] * Rj[0 * 3 + c]
                                           + R[r2 * 3 + 1] * Rj[1 * 3 + c]
                                           + R[r2 * 3 + 2] * Rj[2 * 3 + c];
                    #pragma unroll
                    for (int k = 0; k < 9; ++k) R[k] = Nn[k];
                }
                o[jl * 3 + 0] = t[0];
                o[jl * 3 + 1] = t[1];
                o[jl * 3 + 2] = t[2];
            }
        }

        // ---- Kogge-Stone inclusive scan over the 4 lanes of a sample ----
        #pragma unroll
        for (int d = 1; d <= 2; d *= 2) {
            float LR[9], Lt[3];
            #pragma unroll
            for (int k = 0; k < 9; ++k) LR[k] = __shfl_up(R[k], (unsigned)d);
            #pragma unroll
            for (int c = 0; c < 3; ++c) Lt[c] = __shfl_up(t[c], (unsigned)d);
            if (seg >= d) {
                float nt0 = Lt[0] + LR[0] * t[0] + LR[1] * t[1] + LR[2] * t[2];
                float nt1 = Lt[1] + LR[3] * t[0] + LR[4] * t[1] + LR[5] * t[2];
                float nt2 = Lt[2] + LR[6] * t[0] + LR[7] * t[1] + LR[8] * t[2];
                float Nn[9];
                #pragma unroll
                for (int r2 = 0; r2 < 3; ++r2)
                    #pragma unroll
                    for (int c = 0; c < 3; ++c)
                        Nn[r2 * 3 + c] = LR[r2 * 3 + 0] * R[0 * 3 + c]
                                       + LR[r2 * 3 + 1] * R[1 * 3 + c]
                                       + LR[r2 * 3 + 2] * R[2 * 3 + c];
                #pragma unroll
                for (int k = 0; k < 9; ++k) R[k] = Nn[k];
                t[0] = nt0; t[1] = nt1; t[2] = nt2;
            }
        }

        // Exclusive prefix = inclusive of lane-1 (identity for seg 0).
        float ER[9], Et[3];
        #pragma unroll
        for (int k = 0; k < 9; ++k) ER[k] = __shfl_up(R[k], 1u);
        #pragma unroll
        for (int c = 0; c < 3; ++c) Et[c] = __shfl_up(t[c], 1u);
        if (seg == 0) {
            ER[0] = 1.f; ER[1] = 0.f; ER[2] = 0.f;
            ER[3] = 0.f; ER[4] = 1.f; ER[5] = 0.f;
            ER[6] = 0.f; ER[7] = 0.f; ER[8] = 1.f;
            Et[0] = 0.f; Et[1] = 0.f; Et[2] = 0.f;
        }

        // Fixup: global translation = Et + ER @ local.
        #pragma unroll
        for (int k = 0; k < 6; ++k) {
            const float ox = o[3 * k + 0], oy = o[3 * k + 1], oz = o[3 * k + 2];
            o[3 * k + 0] = Et[0] + ER[0] * ox + ER[1] * oy + ER[2] * oz;
            o[3 * k + 1] = Et[1] + ER[3] * ox + ER[4] * oy + ER[5] * oz;
            o[3 * k + 2] = Et[2] + ER[6] * ox + ER[7] * oy + ER[8] * oz;
        }

        // ---- stage out into front half of buf[cur] (input reads done:
        // lockstep wave, in-order DS), then coalesced float4 store ----
        float2* ob = reinterpret_cast<float2*>(&s_buf[cur][0]);
        #pragma unroll
        for (int q = 0; q < 9; ++q) {
            float2 v; v.x = o[2 * q + 0]; v.y = o[2 * q + 1];
            ob[lane * 9 + q] = v;   // lane*9 odd stride -> minimal bank spread
        }

        const size_t out_base = (size_t)g * (TS * 18);   // 288 float4 per tile
        #pragma unroll
        for (int it = 0; it < 4; ++it)
            aout[out_base + lane + 64 * it] = s_buf[cur][lane + 64 * it];
        if (lane < 32)
            aout[out_base + 256 + lane] = s_buf[cur][256 + lane];
    }
}

extern "C" void kernel_launch(void* const* d_in, const int* in_sizes, int n_in,
                              void* d_out, int out_size, void* d_ws, size_t ws_size,
                              hipStream_t stream) {
    const float* angles = (const float*)d_in[0];   // [N][24][6] f32
    const float* xyz    = (const float*)d_in[1];   // [1][24][3] f32
    float* out = (float*)d_out;

    const int N = in_sizes[0] / (N_JOINTS * 6);    // 131072 = 16 * 8192
    const int ntiles = N / TS;                      // 8192
    const int grid = (ntiles < GRID) ? ntiles : GRID;
    fk_kernel<<<grid, 64, 0, stream>>>(
        reinterpret_cast<const float4*>(angles), xyz,
        reinterpret_cast<float4*>(out), ntiles);
}